// Round 4
// baseline (690.920 us; speedup 1.0000x reference)
//
#include <hip/hip_runtime.h>
#include <hip/hip_bf16.h>

// Problem constants (shapes fixed by the reference)
#define DIM 256          // feature dim (D == H == 256)
#define KDIM 512         // fused K = D(agg) + D(root)

typedef unsigned short ushort_t;
typedef __attribute__((ext_vector_type(8))) short short8;   // 8 x bf16 (4 VGPRs) MFMA A/B frag
typedef __attribute__((ext_vector_type(4))) float f32x4;    // MFMA C/D frag

__device__ __forceinline__ float bf2f(ushort_t u) {
    union { unsigned int i; float f; } c; c.i = ((unsigned int)u) << 16; return c.f;
}
__device__ __forceinline__ ushort_t f2bf(float f) {
    unsigned int x = __float_as_uint(f);
    unsigned int r = (x + 0x7fffu + ((x >> 16) & 1u)) >> 16;
    return (ushort_t)r;
}

// ---------------- edge_index dtype probe ----------------
// int64 storage: odd int32 words are zero high-halves. int32: odd words are random src ids.
__global__ void detect_kernel(const int* __restrict__ ei, int* __restrict__ flag) {
    __shared__ int any;
    if (threadIdx.x == 0) any = 0;
    __syncthreads();
    if (ei[2 * threadIdx.x + 1] != 0) atomicOr(&any, 1);
    __syncthreads();
    if (threadIdx.x == 0) *flag = (any == 0) ? 1 : 0;   // 1 => int64 layout
}

// ---------------- CSR build ----------------

__global__ void hist_kernel(const int* __restrict__ ei, const int* __restrict__ flag,
                            int* __restrict__ deg, int E, int Nn) {
    int e = blockIdx.x * blockDim.x + threadIdx.x;
    if (e < E) {
        int is64 = *flag;
        int d = is64 ? ei[2 * (E + e)] : ei[E + e];   // dst node
        d = (d < 0) ? 0 : (d >= Nn ? Nn - 1 : d);
        atomicAdd(&deg[d], 1);
    }
}

__global__ void scan_kernel(const int* __restrict__ deg, int* __restrict__ row_ptr,
                            int* __restrict__ cursor, int Nn) {
    __shared__ int sdata[1024];
    int t = threadIdx.x;
    int C = (Nn + 1023) / 1024;
    int start = t * C;
    int end = start + C; if (end > Nn) end = Nn; if (start > Nn) start = Nn;
    int sum = 0;
    for (int i = start; i < end; ++i) sum += deg[i];
    sdata[t] = sum;
    __syncthreads();
    for (int off = 1; off < 1024; off <<= 1) {
        int v = (t >= off) ? sdata[t - off] : 0;
        __syncthreads();
        sdata[t] += v;
        __syncthreads();
    }
    int run = sdata[t] - sum;  // exclusive prefix
    for (int i = start; i < end; ++i) {
        row_ptr[i] = run;
        cursor[i] = run;
        run += deg[i];
    }
    if (t == 1023) row_ptr[Nn] = sdata[1023];
}

__global__ void fill_kernel(const int* __restrict__ ei, const int* __restrict__ flag,
                            int* __restrict__ cursor, int* __restrict__ srcs, int E, int Nn) {
    int e = blockIdx.x * blockDim.x + threadIdx.x;
    if (e < E) {
        int is64 = *flag;
        int d = is64 ? ei[2 * (E + e)] : ei[E + e];
        int s = is64 ? ei[2 * e]       : ei[e];
        d = (d < 0) ? 0 : (d >= Nn ? Nn - 1 : d);
        s = (s < 0) ? 0 : (s >= Nn ? Nn - 1 : s);
        int p = atomicAdd(&cursor[d], 1);
        srcs[p] = s;
    }
}

// ---------------- x fp32 -> bf16 convert ----------------

__global__ void convert_kernel(const float* __restrict__ xin, ushort_t* __restrict__ xb, int n4) {
    int i = blockIdx.x * blockDim.x + threadIdx.x;   // over n/4
    if (i < n4) {
        const float4 v = *(const float4*)(xin + (size_t)i * 4);
        ushort4 o;
        o.x = f2bf(v.x); o.y = f2bf(v.y); o.z = f2bf(v.z); o.w = f2bf(v.w);
        *(ushort4*)(xb + (size_t)i * 4) = o;
    }
}

// ---------------- weight pack: Wt[n][k] = bf16( k<256 ? Wrel[k][n] : Wroot[k-256][n] ) ----------------

__global__ void pack_w_kernel(const float* __restrict__ Wrel, const float* __restrict__ Wroot,
                              ushort_t* __restrict__ Wt) {
    int id = blockIdx.x * blockDim.x + threadIdx.x;  // over 256*512
    if (id >= DIM * KDIM) return;
    int n = id >> 9;       // /512
    int k = id & 511;
    float v = (k < DIM) ? Wrel[k * DIM + n] : Wroot[(k - DIM) * DIM + n];
    Wt[id] = f2bf(v);
}

// ---------------- aggregation: one wave per node, bf16 gather, fp32 accumulate, bf16 out ----------------

__global__ __launch_bounds__(256)
void agg_kernel(const ushort_t* __restrict__ xin, const int* __restrict__ row_ptr,
                const int* __restrict__ srcs, ushort_t* __restrict__ aggout, int Nn) {
    int gid = blockIdx.x * blockDim.x + threadIdx.x;
    int node = gid >> 6;
    int lane = gid & 63;
    if (node >= Nn) return;
    int beg = row_ptr[node], end = row_ptr[node + 1];
    float a0 = 0.f, a1 = 0.f, a2 = 0.f, a3 = 0.f;
    int off = lane * 4;
    for (int e = beg; e < end; ++e) {
        int s = srcs[e];
        const ushort4 v = *(const ushort4*)(xin + (size_t)s * DIM + off);
        a0 += bf2f(v.x); a1 += bf2f(v.y); a2 += bf2f(v.z); a3 += bf2f(v.w);
    }
    ushort4 o;
    o.x = f2bf(a0); o.y = f2bf(a1); o.z = f2bf(a2); o.w = f2bf(a3);
    *(ushort4*)(aggout + (size_t)node * DIM + off) = o;
}

// ---------------- fused GEMM: out = elu([agg|root] @ W + bias) ----------------
// 128x128 tile per block, 4 waves (2x2), each 64x64 via 4x4 MFMA 16x16x32 bf16 frags.
// LDS: As[m][k] 128x32, Bs[n][k] 128x32 (Wt pre-packed [n][k]); 16 K-steps of BK=32.
// OUT_F32: layers 1-2 write bf16 hidden, layer 3 writes fp32 d_out.

template <bool OUT_F32>
__global__ __launch_bounds__(256)
void gemm_fused_kernel(const ushort_t* __restrict__ Aagg, const ushort_t* __restrict__ Ax,
                       const ushort_t* __restrict__ Wt, const float* __restrict__ bias,
                       void* __restrict__ outp, int M) {
    __shared__ __align__(16) ushort_t As[128 * 32];
    __shared__ __align__(16) ushort_t Bs[128 * 32];
    const int t = threadIdx.x;
    const int w = t >> 6, l = t & 63;
    const int bm = blockIdx.x, bn = blockIdx.y;

    f32x4 acc[4][4] = {};

    const int sub = l >> 2;    // staging row-within-16
    const int kq  = l & 3;     // 16B chunk within 64B row

    const int r0 = w * 16 + sub;        // rows 0..63 across waves
    const int r1 = 64 + w * 16 + sub;   // rows 64..127
    int n0 = bm * 128 + r0; if (n0 > M - 1) n0 = M - 1;
    int n1 = bm * 128 + r1; if (n1 > M - 1) n1 = M - 1;
    const int c0 = bn * 128 + r0;       // weight rows (always < 256)
    const int c1 = bn * 128 + r1;

    const int mrow = (w >> 1) * 64 + (l & 15);
    const int nrow = (w & 1) * 64 + (l & 15);
    const int koff = (l >> 4) * 8;

    for (int ks = 0; ks < 16; ++ks) {
        const int k0 = ks * 32;
        const ushort_t* Ab = (k0 < DIM) ? (Aagg + k0) : (Ax + (k0 - DIM));
        short8 a0 = *(const short8*)(Ab + (size_t)n0 * DIM + kq * 8);
        short8 a1 = *(const short8*)(Ab + (size_t)n1 * DIM + kq * 8);
        const ushort_t* Wb = Wt + k0 + kq * 8;
        short8 b0 = *(const short8*)(Wb + (size_t)c0 * KDIM);
        short8 b1 = *(const short8*)(Wb + (size_t)c1 * KDIM);
        *(short8*)&As[r0 * 32 + kq * 8] = a0;
        *(short8*)&As[r1 * 32 + kq * 8] = a1;
        *(short8*)&Bs[r0 * 32 + kq * 8] = b0;
        *(short8*)&Bs[r1 * 32 + kq * 8] = b1;
        __syncthreads();

        short8 af[4], bfv[4];
#pragma unroll
        for (int i = 0; i < 4; ++i) {
            af[i]  = *(const short8*)&As[(mrow + i * 16) * 32 + koff];
            bfv[i] = *(const short8*)&Bs[(nrow + i * 16) * 32 + koff];
        }
#pragma unroll
        for (int mi = 0; mi < 4; ++mi)
#pragma unroll
            for (int ni = 0; ni < 4; ++ni)
                acc[mi][ni] = __builtin_amdgcn_mfma_f32_16x16x32_bf16(
                    af[mi], bfv[ni], acc[mi][ni], 0, 0, 0);
        __syncthreads();
    }

    // epilogue: bias + ELU; C/D layout col=lane&15, row=(lane>>4)*4+reg
    const int col0 = bn * 128 + (w & 1) * 64 + (l & 15);
    const int rb   = bm * 128 + (w >> 1) * 64 + ((l >> 4) << 2);
    float bv[4];
#pragma unroll
    for (int ni = 0; ni < 4; ++ni) bv[ni] = bias[col0 + ni * 16];
#pragma unroll
    for (int mi = 0; mi < 4; ++mi) {
#pragma unroll
        for (int r = 0; r < 4; ++r) {
            int node = rb + mi * 16 + r;
            if (node < M) {
#pragma unroll
                for (int ni = 0; ni < 4; ++ni) {
                    float v = acc[mi][ni][r] + bv[ni];
                    v = v > 0.f ? v : (__expf(v) - 1.f);
                    if (OUT_F32)
                        ((float*)outp)[(size_t)node * DIM + col0 + ni * 16] = v;
                    else
                        ((ushort_t*)outp)[(size_t)node * DIM + col0 + ni * 16] = f2bf(v);
                }
            }
        }
    }
}

// ---------------- launcher ----------------
// fp32 in / fp32 out per the reference dtypes. Internals in bf16.
// d_out (51.2 MB fp32) hosts xb (bf16 copy of x) and h1 (bf16 hidden-1) in its
// two halves; both are dead before the layer-3 GEMM overwrites d_out with fp32.
// ws holds CSR + Wt + aggbuf + h2 (~56 MB).

extern "C" void kernel_launch(void* const* d_in, const int* in_sizes, int n_in,
                              void* d_out, int out_size, void* d_ws, size_t ws_size,
                              hipStream_t stream) {
    const float* x  = (const float*)d_in[0];
    const int*   ei = (const int*)d_in[1];
    const float* Wrel[3] = { (const float*)d_in[2], (const float*)d_in[5], (const float*)d_in[8] };
    const float* bias[3] = { (const float*)d_in[3], (const float*)d_in[6], (const float*)d_in[9] };
    const float* Wroot[3]= { (const float*)d_in[4], (const float*)d_in[7], (const float*)d_in[10] };

    const int Nn = in_sizes[0] / DIM;      // 50000
    const int E  = in_sizes[1] / 2;        // 800000

    // workspace bump allocator (1KB aligned)
    char* ws = (char*)d_ws;
    size_t off = 0;
    auto alloc = [&](size_t bytes) {
        char* p = ws + off;
        off = (off + bytes + 1023) & ~(size_t)1023;
        return p;
    };
    int* flag     = (int*)alloc(4);
    int* deg      = (int*)alloc((size_t)Nn * 4);
    int* row_ptr  = (int*)alloc((size_t)(Nn + 1) * 4);
    int* cursor   = (int*)alloc((size_t)Nn * 4);
    int* srcs     = (int*)alloc((size_t)E * 4);
    ushort_t* Wt0 = (ushort_t*)alloc((size_t)DIM * KDIM * 2);
    ushort_t* Wt1 = (ushort_t*)alloc((size_t)DIM * KDIM * 2);
    ushort_t* Wt2 = (ushort_t*)alloc((size_t)DIM * KDIM * 2);
    ushort_t* Wt[3] = { Wt0, Wt1, Wt2 };
    ushort_t* aggbuf = (ushort_t*)alloc((size_t)Nn * DIM * 2);
    ushort_t* h2     = (ushort_t*)alloc((size_t)Nn * DIM * 2);
    (void)ws_size; (void)n_in; (void)out_size;

    ushort_t* xb = (ushort_t*)d_out;            // bf16 x copy (d_out lower half)
    ushort_t* h1 = xb + (size_t)Nn * DIM;       // bf16 hidden-1 (d_out upper half)

    // 1) dtype probe + CSR build
    detect_kernel<<<1, 256, 0, stream>>>(ei, flag);
    hipMemsetAsync(deg, 0, (size_t)Nn * 4, stream);
    hist_kernel<<<(E + 255) / 256, 256, 0, stream>>>(ei, flag, deg, E, Nn);
    scan_kernel<<<1, 1024, 0, stream>>>(deg, row_ptr, cursor, Nn);
    fill_kernel<<<(E + 255) / 256, 256, 0, stream>>>(ei, flag, cursor, srcs, E, Nn);

    // 2) x -> bf16, pack weights to [n][k] fused bf16 layout
    const int n4 = Nn * DIM / 4;
    convert_kernel<<<(n4 + 255) / 256, 256, 0, stream>>>(x, xb, n4);
    for (int L = 0; L < 3; ++L)
        pack_w_kernel<<<(DIM * KDIM + 255) / 256, 256, 0, stream>>>(Wrel[L], Wroot[L], Wt[L]);

    // 3) three GraphConv layers
    const int aggBlocks = (Nn * 64 + 255) / 256;          // one wave per node
    dim3 ggrid((Nn + 127) / 128, 2);

    agg_kernel<<<aggBlocks, 256, 0, stream>>>(xb, row_ptr, srcs, aggbuf, Nn);
    gemm_fused_kernel<false><<<ggrid, 256, 0, stream>>>(aggbuf, xb, Wt[0], bias[0], h1, Nn);

    agg_kernel<<<aggBlocks, 256, 0, stream>>>(h1, row_ptr, srcs, aggbuf, Nn);
    gemm_fused_kernel<false><<<ggrid, 256, 0, stream>>>(aggbuf, h1, Wt[1], bias[1], h2, Nn);

    agg_kernel<<<aggBlocks, 256, 0, stream>>>(h2, row_ptr, srcs, aggbuf, Nn);
    gemm_fused_kernel<true><<<ggrid, 256, 0, stream>>>(aggbuf, h2, Wt[2], bias[2], d_out, Nn);
}

// Round 5
// 589.578 us; speedup vs baseline: 1.1719x; 1.1719x over previous
//
#include <hip/hip_runtime.h>
#include <hip/hip_bf16.h>

// Problem constants (shapes fixed by the reference)
#define DIM 256          // feature dim (D == H == 256)
#define KDIM 512         // fused K = D(agg) + D(root)

typedef unsigned short ushort_t;
typedef __attribute__((ext_vector_type(8))) short short8;   // 8 x bf16 (4 VGPRs) MFMA A/B frag
typedef __attribute__((ext_vector_type(4))) float f32x4;    // MFMA C/D frag

__device__ __forceinline__ float bf2f(ushort_t u) {
    union { unsigned int i; float f; } c; c.i = ((unsigned int)u) << 16; return c.f;
}
__device__ __forceinline__ ushort_t f2bf(float f) {
    unsigned int x = __float_as_uint(f);
    unsigned int r = (x + 0x7fffu + ((x >> 16) & 1u)) >> 16;
    return (ushort_t)r;
}

// ---------------- edge_index dtype probe ----------------
// int64 storage: odd int32 words are zero high-halves. int32: odd words are random src ids.
__global__ void detect_kernel(const int* __restrict__ ei, int* __restrict__ flag) {
    __shared__ int any;
    if (threadIdx.x == 0) any = 0;
    __syncthreads();
    if (ei[2 * threadIdx.x + 1] != 0) atomicOr(&any, 1);
    __syncthreads();
    if (threadIdx.x == 0) *flag = (any == 0) ? 1 : 0;   // 1 => int64 layout
}

// ---------------- CSR build ----------------

__global__ void hist_kernel(const int* __restrict__ ei, const int* __restrict__ flag,
                            int* __restrict__ deg, int E, int Nn) {
    int e = blockIdx.x * blockDim.x + threadIdx.x;
    if (e < E) {
        int is64 = *flag;
        int d = is64 ? ei[2 * (E + e)] : ei[E + e];   // dst node
        d = (d < 0) ? 0 : (d >= Nn ? Nn - 1 : d);
        atomicAdd(&deg[d], 1);
    }
}

// multi-block exclusive scan of deg -> row_ptr/cursor (3 kernels, 1024 elems/block)

__global__ __launch_bounds__(256)
void scan1_kernel(const int* __restrict__ deg, int* __restrict__ partials, int Nn) {
    __shared__ int red[256];
    int t = threadIdx.x;
    int base = blockIdx.x * 1024 + t * 4;
    int s = 0;
    if (base + 3 < Nn) {
        const int4 v = *(const int4*)(deg + base);
        s = v.x + v.y + v.z + v.w;
    } else {
        for (int i = 0; i < 4; ++i) if (base + i < Nn) s += deg[base + i];
    }
    red[t] = s;
    __syncthreads();
    for (int off = 128; off > 0; off >>= 1) {
        if (t < off) red[t] += red[t + off];
        __syncthreads();
    }
    if (t == 0) partials[blockIdx.x] = red[0];
}

__global__ void scan2_kernel(int* __restrict__ partials, int nb) {   // nb <= 64, one wave
    int l = threadIdx.x & 63;
    int orig = (l < nb) ? partials[l] : 0;
    int v = orig;
    for (int off = 1; off < 64; off <<= 1) {
        int u = __shfl_up(v, off, 64);
        if (l >= off) v += u;
    }
    if (l < nb) partials[l] = v - orig;   // exclusive
}

__global__ __launch_bounds__(256)
void scan3_kernel(const int* __restrict__ deg, const int* __restrict__ partials,
                  int* __restrict__ row_ptr, int* __restrict__ cursor, int Nn, int E) {
    __shared__ int sdata[256];
    int t = threadIdx.x;
    int base = blockIdx.x * 1024 + t * 4;
    int d0 = 0, d1 = 0, d2 = 0, d3 = 0;
    if (base + 3 < Nn) {
        const int4 v = *(const int4*)(deg + base);
        d0 = v.x; d1 = v.y; d2 = v.z; d3 = v.w;
    } else {
        if (base + 0 < Nn) d0 = deg[base + 0];
        if (base + 1 < Nn) d1 = deg[base + 1];
        if (base + 2 < Nn) d2 = deg[base + 2];
        if (base + 3 < Nn) d3 = deg[base + 3];
    }
    int tsum = d0 + d1 + d2 + d3;
    sdata[t] = tsum;
    __syncthreads();
    for (int off = 1; off < 256; off <<= 1) {
        int u = (t >= off) ? sdata[t - off] : 0;
        __syncthreads();
        sdata[t] += u;
        __syncthreads();
    }
    int p0 = sdata[t] - tsum + partials[blockIdx.x];
    int p1 = p0 + d0, p2 = p1 + d1, p3 = p2 + d2;
    if (base + 3 < Nn) {
        *(int4*)(row_ptr + base) = make_int4(p0, p1, p2, p3);
        *(int4*)(cursor  + base) = make_int4(p0, p1, p2, p3);
    } else {
        if (base + 0 < Nn) { row_ptr[base + 0] = p0; cursor[base + 0] = p0; }
        if (base + 1 < Nn) { row_ptr[base + 1] = p1; cursor[base + 1] = p1; }
        if (base + 2 < Nn) { row_ptr[base + 2] = p2; cursor[base + 2] = p2; }
        if (base + 3 < Nn) { row_ptr[base + 3] = p3; cursor[base + 3] = p3; }
    }
    if (blockIdx.x == 0 && t == 0) row_ptr[Nn] = E;   // total = E (every edge counted once)
}

__global__ void fill_kernel(const int* __restrict__ ei, const int* __restrict__ flag,
                            int* __restrict__ cursor, int* __restrict__ srcs, int E, int Nn) {
    int e = blockIdx.x * blockDim.x + threadIdx.x;
    if (e < E) {
        int is64 = *flag;
        int d = is64 ? ei[2 * (E + e)] : ei[E + e];
        int s = is64 ? ei[2 * e]       : ei[e];
        d = (d < 0) ? 0 : (d >= Nn ? Nn - 1 : d);
        s = (s < 0) ? 0 : (s >= Nn ? Nn - 1 : s);
        int p = atomicAdd(&cursor[d], 1);
        srcs[p] = s;
    }
}

// ---------------- x fp32 -> bf16 convert ----------------

__global__ void convert_kernel(const float* __restrict__ xin, ushort_t* __restrict__ xb, int n4) {
    int i = blockIdx.x * blockDim.x + threadIdx.x;   // over n/4
    if (i < n4) {
        const float4 v = *(const float4*)(xin + (size_t)i * 4);
        ushort4 o;
        o.x = f2bf(v.x); o.y = f2bf(v.y); o.z = f2bf(v.z); o.w = f2bf(v.w);
        *(ushort4*)(xb + (size_t)i * 4) = o;
    }
}

// ---------------- weight pack: Wt[n][k] = bf16( k<256 ? Wrel[k][n] : Wroot[k-256][n] ) ----------------

__global__ void pack_w_kernel(const float* __restrict__ Wrel, const float* __restrict__ Wroot,
                              ushort_t* __restrict__ Wt) {
    int id = blockIdx.x * blockDim.x + threadIdx.x;  // over 256*512
    if (id >= DIM * KDIM) return;
    int n = id >> 9;       // /512
    int k = id & 511;
    float v = (k < DIM) ? Wrel[k * DIM + n] : Wroot[(k - DIM) * DIM + n];
    Wt[id] = f2bf(v);
}

// ---------------- aggregation: one wave per node, bf16 gather, fp32 accumulate, bf16 out ----------------

__global__ __launch_bounds__(256)
void agg_kernel(const ushort_t* __restrict__ xin, const int* __restrict__ row_ptr,
                const int* __restrict__ srcs, ushort_t* __restrict__ aggout, int Nn) {
    int gid = blockIdx.x * blockDim.x + threadIdx.x;
    int node = gid >> 6;
    int lane = gid & 63;
    if (node >= Nn) return;
    int beg = row_ptr[node], end = row_ptr[node + 1];
    float a0 = 0.f, a1 = 0.f, a2 = 0.f, a3 = 0.f;
    int off = lane * 4;
    for (int e = beg; e < end; ++e) {
        int s = srcs[e];
        const ushort4 v = *(const ushort4*)(xin + (size_t)s * DIM + off);
        a0 += bf2f(v.x); a1 += bf2f(v.y); a2 += bf2f(v.z); a3 += bf2f(v.w);
    }
    ushort4 o;
    o.x = f2bf(a0); o.y = f2bf(a1); o.z = f2bf(a2); o.w = f2bf(a3);
    *(ushort4*)(aggout + (size_t)node * DIM + off) = o;
}

// ---------------- fused GEMM: out = elu([agg|root] @ W + bias) ----------------
// 128x128 tile per block, 4 waves (2x2), each 64x64 via 4x4 MFMA 16x16x32 bf16 frags.
// LDS: As[m][k] 128x32, Bs[n][k] 128x32 (Wt pre-packed [n][k]); 16 K-steps of BK=32.
// OUT_F32: layers 1-2 write bf16 hidden, layer 3 writes fp32 d_out.

template <bool OUT_F32>
__global__ __launch_bounds__(256)
void gemm_fused_kernel(const ushort_t* __restrict__ Aagg, const ushort_t* __restrict__ Ax,
                       const ushort_t* __restrict__ Wt, const float* __restrict__ bias,
                       void* __restrict__ outp, int M) {
    __shared__ __align__(16) ushort_t As[128 * 32];
    __shared__ __align__(16) ushort_t Bs[128 * 32];
    const int t = threadIdx.x;
    const int w = t >> 6, l = t & 63;
    const int bm = blockIdx.x, bn = blockIdx.y;

    f32x4 acc[4][4] = {};

    const int sub = l >> 2;    // staging row-within-16
    const int kq  = l & 3;     // 16B chunk within 64B row

    const int r0 = w * 16 + sub;        // rows 0..63 across waves
    const int r1 = 64 + w * 16 + sub;   // rows 64..127
    int n0 = bm * 128 + r0; if (n0 > M - 1) n0 = M - 1;
    int n1 = bm * 128 + r1; if (n1 > M - 1) n1 = M - 1;
    const int c0 = bn * 128 + r0;       // weight rows (always < 256)
    const int c1 = bn * 128 + r1;

    const int mrow = (w >> 1) * 64 + (l & 15);
    const int nrow = (w & 1) * 64 + (l & 15);
    const int koff = (l >> 4) * 8;

    for (int ks = 0; ks < 16; ++ks) {
        const int k0 = ks * 32;
        const ushort_t* Ab = (k0 < DIM) ? (Aagg + k0) : (Ax + (k0 - DIM));
        short8 a0 = *(const short8*)(Ab + (size_t)n0 * DIM + kq * 8);
        short8 a1 = *(const short8*)(Ab + (size_t)n1 * DIM + kq * 8);
        const ushort_t* Wb = Wt + k0 + kq * 8;
        short8 b0 = *(const short8*)(Wb + (size_t)c0 * KDIM);
        short8 b1 = *(const short8*)(Wb + (size_t)c1 * KDIM);
        *(short8*)&As[r0 * 32 + kq * 8] = a0;
        *(short8*)&As[r1 * 32 + kq * 8] = a1;
        *(short8*)&Bs[r0 * 32 + kq * 8] = b0;
        *(short8*)&Bs[r1 * 32 + kq * 8] = b1;
        __syncthreads();

        short8 af[4], bfv[4];
#pragma unroll
        for (int i = 0; i < 4; ++i) {
            af[i]  = *(const short8*)&As[(mrow + i * 16) * 32 + koff];
            bfv[i] = *(const short8*)&Bs[(nrow + i * 16) * 32 + koff];
        }
#pragma unroll
        for (int mi = 0; mi < 4; ++mi)
#pragma unroll
            for (int ni = 0; ni < 4; ++ni)
                acc[mi][ni] = __builtin_amdgcn_mfma_f32_16x16x32_bf16(
                    af[mi], bfv[ni], acc[mi][ni], 0, 0, 0);
        __syncthreads();
    }

    // epilogue: bias + ELU; C/D layout col=lane&15, row=(lane>>4)*4+reg
    const int col0 = bn * 128 + (w & 1) * 64 + (l & 15);
    const int rb   = bm * 128 + (w >> 1) * 64 + ((l >> 4) << 2);
    float bv[4];
#pragma unroll
    for (int ni = 0; ni < 4; ++ni) bv[ni] = bias[col0 + ni * 16];
#pragma unroll
    for (int mi = 0; mi < 4; ++mi) {
#pragma unroll
        for (int r = 0; r < 4; ++r) {
            int node = rb + mi * 16 + r;
            if (node < M) {
#pragma unroll
                for (int ni = 0; ni < 4; ++ni) {
                    float v = acc[mi][ni][r] + bv[ni];
                    v = v > 0.f ? v : (__expf(v) - 1.f);
                    if (OUT_F32)
                        ((float*)outp)[(size_t)node * DIM + col0 + ni * 16] = v;
                    else
                        ((ushort_t*)outp)[(size_t)node * DIM + col0 + ni * 16] = f2bf(v);
                }
            }
        }
    }
}

// ---------------- launcher ----------------
// fp32 in / fp32 out per the reference dtypes. Internals in bf16.
// d_out (51.2 MB fp32) hosts xb (bf16 copy of x) and h1 (bf16 hidden-1) in its
// two halves; both are dead before the layer-3 GEMM overwrites d_out with fp32.

extern "C" void kernel_launch(void* const* d_in, const int* in_sizes, int n_in,
                              void* d_out, int out_size, void* d_ws, size_t ws_size,
                              hipStream_t stream) {
    const float* x  = (const float*)d_in[0];
    const int*   ei = (const int*)d_in[1];
    const float* Wrel[3] = { (const float*)d_in[2], (const float*)d_in[5], (const float*)d_in[8] };
    const float* bias[3] = { (const float*)d_in[3], (const float*)d_in[6], (const float*)d_in[9] };
    const float* Wroot[3]= { (const float*)d_in[4], (const float*)d_in[7], (const float*)d_in[10] };

    const int Nn = in_sizes[0] / DIM;      // 50000
    const int E  = in_sizes[1] / 2;        // 800000

    // workspace bump allocator (1KB aligned)
    char* ws = (char*)d_ws;
    size_t off = 0;
    auto alloc = [&](size_t bytes) {
        char* p = ws + off;
        off = (off + bytes + 1023) & ~(size_t)1023;
        return p;
    };
    int* flag     = (int*)alloc(4);
    int* deg      = (int*)alloc((size_t)Nn * 4);
    int* row_ptr  = (int*)alloc((size_t)(Nn + 1) * 4);
    int* cursor   = (int*)alloc((size_t)Nn * 4);
    int* partials = (int*)alloc(64 * 4);
    int* srcs     = (int*)alloc((size_t)E * 4);
    ushort_t* Wt0 = (ushort_t*)alloc((size_t)DIM * KDIM * 2);
    ushort_t* Wt1 = (ushort_t*)alloc((size_t)DIM * KDIM * 2);
    ushort_t* Wt2 = (ushort_t*)alloc((size_t)DIM * KDIM * 2);
    ushort_t* Wt[3] = { Wt0, Wt1, Wt2 };
    ushort_t* aggbuf = (ushort_t*)alloc((size_t)Nn * DIM * 2);
    ushort_t* h2     = (ushort_t*)alloc((size_t)Nn * DIM * 2);
    (void)ws_size; (void)n_in; (void)out_size;

    ushort_t* xb = (ushort_t*)d_out;            // bf16 x copy (d_out lower half)
    ushort_t* h1 = xb + (size_t)Nn * DIM;       // bf16 hidden-1 (d_out upper half)

    // 1) dtype probe + CSR build (multi-block scan)
    const int nb = (Nn + 1023) / 1024;          // 49 scan blocks
    detect_kernel<<<1, 256, 0, stream>>>(ei, flag);
    hipMemsetAsync(deg, 0, (size_t)Nn * 4, stream);
    hist_kernel<<<(E + 255) / 256, 256, 0, stream>>>(ei, flag, deg, E, Nn);
    scan1_kernel<<<nb, 256, 0, stream>>>(deg, partials, Nn);
    scan2_kernel<<<1, 64, 0, stream>>>(partials, nb);
    scan3_kernel<<<nb, 256, 0, stream>>>(deg, partials, row_ptr, cursor, Nn, E);
    fill_kernel<<<(E + 255) / 256, 256, 0, stream>>>(ei, flag, cursor, srcs, E, Nn);

    // 2) x -> bf16, pack weights to [n][k] fused bf16 layout
    const int n4 = Nn * DIM / 4;
    convert_kernel<<<(n4 + 255) / 256, 256, 0, stream>>>(x, xb, n4);
    for (int L = 0; L < 3; ++L)
        pack_w_kernel<<<(DIM * KDIM + 255) / 256, 256, 0, stream>>>(Wrel[L], Wroot[L], Wt[L]);

    // 3) three GraphConv layers
    const int aggBlocks = (Nn * 64 + 255) / 256;          // one wave per node
    dim3 ggrid((Nn + 127) / 128, 2);

    agg_kernel<<<aggBlocks, 256, 0, stream>>>(xb, row_ptr, srcs, aggbuf, Nn);
    gemm_fused_kernel<false><<<ggrid, 256, 0, stream>>>(aggbuf, xb, Wt[0], bias[0], h1, Nn);

    agg_kernel<<<aggBlocks, 256, 0, stream>>>(h1, row_ptr, srcs, aggbuf, Nn);
    gemm_fused_kernel<false><<<ggrid, 256, 0, stream>>>(aggbuf, h1, Wt[1], bias[1], h2, Nn);

    agg_kernel<<<aggBlocks, 256, 0, stream>>>(h2, row_ptr, srcs, aggbuf, Nn);
    gemm_fused_kernel<true><<<ggrid, 256, 0, stream>>>(aggbuf, h2, Wt[2], bias[2], d_out, Nn);
}

// Round 6
// 488.588 us; speedup vs baseline: 1.4141x; 1.2067x over previous
//
#include <hip/hip_runtime.h>
#include <hip/hip_bf16.h>

// Problem constants (shapes fixed by the reference)
#define DIM 256          // feature dim (D == H == 256)
#define KDIM 512         // fused K = D(agg) + D(root)

typedef unsigned short ushort_t;
typedef __attribute__((ext_vector_type(8))) short short8;   // 8 x bf16 (4 VGPRs) MFMA A/B frag
typedef __attribute__((ext_vector_type(4))) float f32x4;    // MFMA C/D frag

__device__ __forceinline__ float bf2f(ushort_t u) {
    union { unsigned int i; float f; } c; c.i = ((unsigned int)u) << 16; return c.f;
}
__device__ __forceinline__ ushort_t f2bf(float f) {
    unsigned int x = __float_as_uint(f);
    unsigned int r = (x + 0x7fffu + ((x >> 16) & 1u)) >> 16;
    return (ushort_t)r;
}

// async global->LDS, 16B/lane; LDS dest = wave-uniform base + lane*16
__device__ __forceinline__ void gload_lds16(const ushort_t* g, ushort_t* l) {
    __builtin_amdgcn_global_load_lds(
        (const __attribute__((address_space(1))) unsigned int*)g,
        (__attribute__((address_space(3))) unsigned int*)l, 16, 0, 0);
}

// ---------------- edge_index dtype probe ----------------
__global__ void detect_kernel(const int* __restrict__ ei, int* __restrict__ flag) {
    __shared__ int any;
    if (threadIdx.x == 0) any = 0;
    __syncthreads();
    if (ei[2 * threadIdx.x + 1] != 0) atomicOr(&any, 1);
    __syncthreads();
    if (threadIdx.x == 0) *flag = (any == 0) ? 1 : 0;   // 1 => int64 layout
}

// ---------------- CSR build ----------------

__global__ void hist_kernel(const int* __restrict__ ei, const int* __restrict__ flag,
                            int* __restrict__ deg, int E, int Nn) {
    int e = blockIdx.x * blockDim.x + threadIdx.x;
    if (e < E) {
        int is64 = *flag;
        int d = is64 ? ei[2 * (E + e)] : ei[E + e];   // dst node
        d = (d < 0) ? 0 : (d >= Nn ? Nn - 1 : d);
        atomicAdd(&deg[d], 1);
    }
}

__global__ __launch_bounds__(256)
void scan1_kernel(const int* __restrict__ deg, int* __restrict__ partials, int Nn) {
    __shared__ int red[256];
    int t = threadIdx.x;
    int base = blockIdx.x * 1024 + t * 4;
    int s = 0;
    if (base + 3 < Nn) {
        const int4 v = *(const int4*)(deg + base);
        s = v.x + v.y + v.z + v.w;
    } else {
        for (int i = 0; i < 4; ++i) if (base + i < Nn) s += deg[base + i];
    }
    red[t] = s;
    __syncthreads();
    for (int off = 128; off > 0; off >>= 1) {
        if (t < off) red[t] += red[t + off];
        __syncthreads();
    }
    if (t == 0) partials[blockIdx.x] = red[0];
}

__global__ void scan2_kernel(int* __restrict__ partials, int nb) {   // nb <= 64, one wave
    int l = threadIdx.x & 63;
    int orig = (l < nb) ? partials[l] : 0;
    int v = orig;
    for (int off = 1; off < 64; off <<= 1) {
        int u = __shfl_up(v, off, 64);
        if (l >= off) v += u;
    }
    if (l < nb) partials[l] = v - orig;   // exclusive
}

__global__ __launch_bounds__(256)
void scan3_kernel(const int* __restrict__ deg, const int* __restrict__ partials,
                  int* __restrict__ row_ptr, int* __restrict__ cursor, int Nn, int E) {
    __shared__ int sdata[256];
    int t = threadIdx.x;
    int base = blockIdx.x * 1024 + t * 4;
    int d0 = 0, d1 = 0, d2 = 0, d3 = 0;
    if (base + 3 < Nn) {
        const int4 v = *(const int4*)(deg + base);
        d0 = v.x; d1 = v.y; d2 = v.z; d3 = v.w;
    } else {
        if (base + 0 < Nn) d0 = deg[base + 0];
        if (base + 1 < Nn) d1 = deg[base + 1];
        if (base + 2 < Nn) d2 = deg[base + 2];
        if (base + 3 < Nn) d3 = deg[base + 3];
    }
    int tsum = d0 + d1 + d2 + d3;
    sdata[t] = tsum;
    __syncthreads();
    for (int off = 1; off < 256; off <<= 1) {
        int u = (t >= off) ? sdata[t - off] : 0;
        __syncthreads();
        sdata[t] += u;
        __syncthreads();
    }
    int p0 = sdata[t] - tsum + partials[blockIdx.x];
    int p1 = p0 + d0, p2 = p1 + d1, p3 = p2 + d2;
    if (base + 3 < Nn) {
        *(int4*)(row_ptr + base) = make_int4(p0, p1, p2, p3);
        *(int4*)(cursor  + base) = make_int4(p0, p1, p2, p3);
    } else {
        if (base + 0 < Nn) { row_ptr[base + 0] = p0; cursor[base + 0] = p0; }
        if (base + 1 < Nn) { row_ptr[base + 1] = p1; cursor[base + 1] = p1; }
        if (base + 2 < Nn) { row_ptr[base + 2] = p2; cursor[base + 2] = p2; }
        if (base + 3 < Nn) { row_ptr[base + 3] = p3; cursor[base + 3] = p3; }
    }
    if (blockIdx.x == 0 && t == 0) row_ptr[Nn] = E;
}

__global__ void fill_kernel(const int* __restrict__ ei, const int* __restrict__ flag,
                            int* __restrict__ cursor, int* __restrict__ srcs, int E, int Nn) {
    int e = blockIdx.x * blockDim.x + threadIdx.x;
    if (e < E) {
        int is64 = *flag;
        int d = is64 ? ei[2 * (E + e)] : ei[E + e];
        int s = is64 ? ei[2 * e]       : ei[e];
        d = (d < 0) ? 0 : (d >= Nn ? Nn - 1 : d);
        s = (s < 0) ? 0 : (s >= Nn ? Nn - 1 : s);
        int p = atomicAdd(&cursor[d], 1);
        srcs[p] = s;
    }
}

// ---------------- x fp32 -> bf16 convert ----------------

__global__ void convert_kernel(const float* __restrict__ xin, ushort_t* __restrict__ xb, int n4) {
    int i = blockIdx.x * blockDim.x + threadIdx.x;   // over n/4
    if (i < n4) {
        const float4 v = *(const float4*)(xin + (size_t)i * 4);
        ushort4 o;
        o.x = f2bf(v.x); o.y = f2bf(v.y); o.z = f2bf(v.z); o.w = f2bf(v.w);
        *(ushort4*)(xb + (size_t)i * 4) = o;
    }
}

// ---------------- weight pack: Wt[n][k] = bf16( k<256 ? Wrel[k][n] : Wroot[k-256][n] ) ----------------

__global__ void pack_w_kernel(const float* __restrict__ Wrel, const float* __restrict__ Wroot,
                              ushort_t* __restrict__ Wt) {
    int id = blockIdx.x * blockDim.x + threadIdx.x;  // over 256*512
    if (id >= DIM * KDIM) return;
    int n = id >> 9;       // /512
    int k = id & 511;
    float v = (k < DIM) ? Wrel[k * DIM + n] : Wroot[(k - DIM) * DIM + n];
    Wt[id] = f2bf(v);
}

// ---------------- aggregation: one wave per node; edge loop unrolled x4 for MLP ----------------

__global__ __launch_bounds__(256)
void agg_kernel(const ushort_t* __restrict__ xin, const int* __restrict__ row_ptr,
                const int* __restrict__ srcs, ushort_t* __restrict__ aggout, int Nn) {
    int gid = blockIdx.x * blockDim.x + threadIdx.x;
    int node = gid >> 6;
    int lane = gid & 63;
    if (node >= Nn) return;
    int beg = row_ptr[node], end = row_ptr[node + 1];
    float a0 = 0.f, a1 = 0.f, a2 = 0.f, a3 = 0.f;
    const int off = lane * 4;
    int e = beg;
    for (; e + 3 < end; e += 4) {
        int s0 = srcs[e], s1 = srcs[e + 1], s2 = srcs[e + 2], s3 = srcs[e + 3];
        const ushort4 v0 = *(const ushort4*)(xin + (size_t)s0 * DIM + off);
        const ushort4 v1 = *(const ushort4*)(xin + (size_t)s1 * DIM + off);
        const ushort4 v2 = *(const ushort4*)(xin + (size_t)s2 * DIM + off);
        const ushort4 v3 = *(const ushort4*)(xin + (size_t)s3 * DIM + off);
        a0 += bf2f(v0.x); a1 += bf2f(v0.y); a2 += bf2f(v0.z); a3 += bf2f(v0.w);
        a0 += bf2f(v1.x); a1 += bf2f(v1.y); a2 += bf2f(v1.z); a3 += bf2f(v1.w);
        a0 += bf2f(v2.x); a1 += bf2f(v2.y); a2 += bf2f(v2.z); a3 += bf2f(v2.w);
        a0 += bf2f(v3.x); a1 += bf2f(v3.y); a2 += bf2f(v3.z); a3 += bf2f(v3.w);
    }
    for (; e < end; ++e) {
        int s = srcs[e];
        const ushort4 v = *(const ushort4*)(xin + (size_t)s * DIM + off);
        a0 += bf2f(v.x); a1 += bf2f(v.y); a2 += bf2f(v.z); a3 += bf2f(v.w);
    }
    ushort4 o;
    o.x = f2bf(a0); o.y = f2bf(a1); o.z = f2bf(a2); o.w = f2bf(a3);
    *(ushort4*)(aggout + (size_t)node * DIM + off) = o;
}

// ---------------- fused GEMM: out = elu([agg|root] @ W + bias) ----------------
// 128x128 tile, 4 waves (2x2), 4x4 MFMA 16x16x32 bf16 frags per wave.
// Staging via global_load_lds width=16: per wave 1KB/instr, LDS dest = base + lane*16
// (lane l -> LDS byte offset 64*(l>>2)+16*(l&3) == 16*l, wave base = w*1024). [m97 pattern]

template <bool OUT_F32>
__global__ __launch_bounds__(256)
void gemm_fused_kernel(const ushort_t* __restrict__ Aagg, const ushort_t* __restrict__ Ax,
                       const ushort_t* __restrict__ Wt, const float* __restrict__ bias,
                       void* __restrict__ outp, int M) {
    __shared__ __align__(16) ushort_t As[128 * 32];
    __shared__ __align__(16) ushort_t Bs[128 * 32];
    const int t = threadIdx.x;
    const int w = t >> 6, l = t & 63;
    const int bm = blockIdx.x, bn = blockIdx.y;

    f32x4 acc[4][4] = {};

    const int sub = l >> 2;    // staging row-within-16
    const int kq  = l & 3;     // 16B chunk within 64B row

    ushort_t* AsB0 = &As[(w * 16) * 32];
    ushort_t* AsB1 = &As[(64 + w * 16) * 32];
    ushort_t* BsB0 = &Bs[(w * 16) * 32];
    ushort_t* BsB1 = &Bs[(64 + w * 16) * 32];

    const int r0 = w * 16 + sub;        // rows 0..63 across waves
    const int r1 = 64 + w * 16 + sub;   // rows 64..127
    int n0 = bm * 128 + r0; if (n0 > M - 1) n0 = M - 1;
    int n1 = bm * 128 + r1; if (n1 > M - 1) n1 = M - 1;
    const int c0 = bn * 128 + r0;       // weight rows (always < 256)
    const int c1 = bn * 128 + r1;

    const int mrow = (w >> 1) * 64 + (l & 15);
    const int nrow = (w & 1) * 64 + (l & 15);
    const int koff = (l >> 4) * 8;

    for (int ks = 0; ks < 16; ++ks) {
        const int k0 = ks * 32;
        const ushort_t* Ab = (k0 < DIM) ? (Aagg + k0) : (Ax + (k0 - DIM));
        gload_lds16(Ab + (size_t)n0 * DIM + kq * 8, AsB0);
        gload_lds16(Ab + (size_t)n1 * DIM + kq * 8, AsB1);
        const ushort_t* Wb = Wt + k0 + kq * 8;
        gload_lds16(Wb + (size_t)c0 * KDIM, BsB0);
        gload_lds16(Wb + (size_t)c1 * KDIM, BsB1);
        __syncthreads();   // drains vmcnt(0): staging complete

        short8 af[4], bfv[4];
#pragma unroll
        for (int i = 0; i < 4; ++i) {
            af[i]  = *(const short8*)&As[(mrow + i * 16) * 32 + koff];
            bfv[i] = *(const short8*)&Bs[(nrow + i * 16) * 32 + koff];
        }
#pragma unroll
        for (int mi = 0; mi < 4; ++mi)
#pragma unroll
            for (int ni = 0; ni < 4; ++ni)
                acc[mi][ni] = __builtin_amdgcn_mfma_f32_16x16x32_bf16(
                    af[mi], bfv[ni], acc[mi][ni], 0, 0, 0);
        __syncthreads();
    }

    // epilogue: bias + ELU; C/D layout col=lane&15, row=(lane>>4)*4+reg
    const int col0 = bn * 128 + (w & 1) * 64 + (l & 15);
    const int rb   = bm * 128 + (w >> 1) * 64 + ((l >> 4) << 2);
    float bv[4];
#pragma unroll
    for (int ni = 0; ni < 4; ++ni) bv[ni] = bias[col0 + ni * 16];
#pragma unroll
    for (int mi = 0; mi < 4; ++mi) {
#pragma unroll
        for (int r = 0; r < 4; ++r) {
            int node = rb + mi * 16 + r;
            if (node < M) {
#pragma unroll
                for (int ni = 0; ni < 4; ++ni) {
                    float v = acc[mi][ni][r] + bv[ni];
                    v = v > 0.f ? v : (__expf(v) - 1.f);
                    if (OUT_F32)
                        ((float*)outp)[(size_t)node * DIM + col0 + ni * 16] = v;
                    else
                        ((ushort_t*)outp)[(size_t)node * DIM + col0 + ni * 16] = f2bf(v);
                }
            }
        }
    }
}

// ---------------- launcher ----------------
// fp32 in / fp32 out per the reference dtypes. Internals in bf16.
// d_out hosts xb and h1 (both dead before layer-3 fp32 overwrite).

extern "C" void kernel_launch(void* const* d_in, const int* in_sizes, int n_in,
                              void* d_out, int out_size, void* d_ws, size_t ws_size,
                              hipStream_t stream) {
    const float* x  = (const float*)d_in[0];
    const int*   ei = (const int*)d_in[1];
    const float* Wrel[3] = { (const float*)d_in[2], (const float*)d_in[5], (const float*)d_in[8] };
    const float* bias[3] = { (const float*)d_in[3], (const float*)d_in[6], (const float*)d_in[9] };
    const float* Wroot[3]= { (const float*)d_in[4], (const float*)d_in[7], (const float*)d_in[10] };

    const int Nn = in_sizes[0] / DIM;      // 50000
    const int E  = in_sizes[1] / 2;        // 800000

    char* ws = (char*)d_ws;
    size_t off = 0;
    auto alloc = [&](size_t bytes) {
        char* p = ws + off;
        off = (off + bytes + 1023) & ~(size_t)1023;
        return p;
    };
    int* flag     = (int*)alloc(4);
    int* deg      = (int*)alloc((size_t)Nn * 4);
    int* row_ptr  = (int*)alloc((size_t)(Nn + 1) * 4);
    int* cursor   = (int*)alloc((size_t)Nn * 4);
    int* partials = (int*)alloc(64 * 4);
    int* srcs     = (int*)alloc((size_t)E * 4);
    ushort_t* Wt0 = (ushort_t*)alloc((size_t)DIM * KDIM * 2);
    ushort_t* Wt1 = (ushort_t*)alloc((size_t)DIM * KDIM * 2);
    ushort_t* Wt2 = (ushort_t*)alloc((size_t)DIM * KDIM * 2);
    ushort_t* Wt[3] = { Wt0, Wt1, Wt2 };
    ushort_t* aggbuf = (ushort_t*)alloc((size_t)Nn * DIM * 2);
    ushort_t* h2     = (ushort_t*)alloc((size_t)Nn * DIM * 2);
    (void)ws_size; (void)n_in; (void)out_size;

    ushort_t* xb = (ushort_t*)d_out;            // bf16 x copy (d_out lower half)
    ushort_t* h1 = xb + (size_t)Nn * DIM;       // bf16 hidden-1 (d_out upper half)

    // 1) dtype probe + CSR build (multi-block scan)
    const int nb = (Nn + 1023) / 1024;          // 49 scan blocks
    detect_kernel<<<1, 256, 0, stream>>>(ei, flag);
    hipMemsetAsync(deg, 0, (size_t)Nn * 4, stream);
    hist_kernel<<<(E + 255) / 256, 256, 0, stream>>>(ei, flag, deg, E, Nn);
    scan1_kernel<<<nb, 256, 0, stream>>>(deg, partials, Nn);
    scan2_kernel<<<1, 64, 0, stream>>>(partials, nb);
    scan3_kernel<<<nb, 256, 0, stream>>>(deg, partials, row_ptr, cursor, Nn, E);
    fill_kernel<<<(E + 255) / 256, 256, 0, stream>>>(ei, flag, cursor, srcs, E, Nn);

    // 2) x -> bf16, pack weights to [n][k] fused bf16 layout
    const int n4 = Nn * DIM / 4;
    convert_kernel<<<(n4 + 255) / 256, 256, 0, stream>>>(x, xb, n4);
    for (int L = 0; L < 3; ++L)
        pack_w_kernel<<<(DIM * KDIM + 255) / 256, 256, 0, stream>>>(Wrel[L], Wroot[L], Wt[L]);

    // 3) three GraphConv layers
    const int aggBlocks = (Nn * 64 + 255) / 256;          // one wave per node
    dim3 ggrid((Nn + 127) / 128, 2);

    agg_kernel<<<aggBlocks, 256, 0, stream>>>(xb, row_ptr, srcs, aggbuf, Nn);
    gemm_fused_kernel<false><<<ggrid, 256, 0, stream>>>(aggbuf, xb, Wt[0], bias[0], h1, Nn);

    agg_kernel<<<aggBlocks, 256, 0, stream>>>(h1, row_ptr, srcs, aggbuf, Nn);
    gemm_fused_kernel<false><<<ggrid, 256, 0, stream>>>(aggbuf, h1, Wt[1], bias[1], h2, Nn);

    agg_kernel<<<aggBlocks, 256, 0, stream>>>(h2, row_ptr, srcs, aggbuf, Nn);
    gemm_fused_kernel<true><<<ggrid, 256, 0, stream>>>(aggbuf, h2, Wt[2], bias[2], d_out, Nn);
}